// Round 2
// baseline (74.310 us; speedup 1.0000x reference)
//
#include <hip/hip_runtime.h>

#define SEQ   512
#define BATCH 256
#define NH    7   // helper partial slots (waves 1..7)

// Uniform-index lane broadcast via v_readlane (index must be SGPR/imm).
__device__ __forceinline__ float bcast_f(float v, int srcLane) {
    return __int_as_float(__builtin_amdgcn_readlane(__float_as_int(v), srcLane));
}
// gfx950: v_log_f32 is log2, v_exp_f32 is exp2.
__device__ __forceinline__ float flog2(float x) { return __builtin_amdgcn_logf(x); }
__device__ __forceinline__ float fexp2(float x) { return __builtin_amdgcn_exp2f(x); }
// Barrier draining only LDS ops (lgkmcnt); __syncthreads() would also drain vmcnt.
__device__ __forceinline__ void lds_barrier() {
    __asm__ __volatile__("s_waitcnt lgkmcnt(0)\ns_barrier" ::: "memory");
}

// Helper wave phase loop. All readlane indices are SGPR-uniform (start from
// readfirstlane'd wid). x-only work (diag tables, panel L, deep xj) is
// computed one phase EARLY, off the post-publish critical path.
template <int CNT>
__device__ __forceinline__ void run_helper(const int start, const int hidx,
                                           const int lane, const float a,
                                           const float c,
                                           float (&x_lds)[SEQ],
                                           float (&expm_lds)[SEQ],
                                           float (&part_lds)[NH][8][64],
                                           float2 (&tbl)[2][64][64]) {
    float Lp[CNT];   // panel L: L(rows J, cols J-1), computed during phase J-1
    float xjd[CNT];  // deep col x values (block J-1), extracted during phase J-1
    for (int J = 0; J < 8; ++J) {
        float pj[CNT];
        if (J > 0) {
            // ---- pre-B1 critical path: only the expm-dependent part.
            const float evec = expm_lds[((J - 1) << 6) | lane];
            const float pvec = -fmaf(c, evec, a);   // p for all 64 cols, 1 op
#pragma unroll
            for (int k = 0; k < CNT; ++k) pj[k] = bcast_f(pvec, start + k);
            // panel: cols J-1 -> rows J, L precomputed last phase.
            float acc0 = 0.0f, acc1 = 0.0f;
#pragma unroll
            for (int k = 0; k < CNT; ++k) {
                const float t = fexp2(pj[k] * Lp[k]);
                if (k & 1) acc1 += t; else acc0 += t;
            }
            part_lds[hidx][J][lane] += acc0 + acc1;
        }
        lds_barrier();  // B1: panel partials for row block J ready

        if (J > 0 && J < 7) {
            // ---- deep: cols J-1 -> rows J+1..7 (overlaps wave0's diagonal).
            float xr = x_lds[((J + 1) << 6) | lane];
            for (int R = J + 1; R < 8; ++R) {
                const int Rn = (R < 7) ? R + 1 : R;              // prefetch
                const float xr_next = x_lds[(Rn << 6) | lane];
                float acc0 = 0.0f, acc1 = 0.0f;
#pragma unroll
                for (int k = 0; k < CNT; ++k) {
                    const float L = flog2(fmaxf(xr - xjd[k], 1.0f));
                    const float t = fexp2(pj[k] * L);
                    if (k & 1) acc1 += t; else acc0 += t;
                }
                part_lds[hidx][R][lane] += acc0 + acc1;
                xr = xr_next;
            }
        }
        if (J < 7) {
            // ---- x-only precompute for phase J+1 (overlaps the diagonal):
            // (1) diag table for block J+1 (consumed by wave0 next phase),
            // (2) panel L (rows J+1, cols J), (3) deep xj (cols J).
            const float xr1 = x_lds[((J + 1) << 6) | lane];  // rows & cols of block J+1
            const float xvJ = x_lds[(J << 6) | lane];        // cols of block J
#pragma unroll
            for (int k = 0; k < CNT; ++k) {
                const float xj = bcast_f(xr1, start + k);
                const float L  = flog2(fmaxf(xr1 - xj, 1.0f));
                tbl[(J + 1) & 1][start + k][lane] = make_float2(-c * L, -a * L);
            }
#pragma unroll
            for (int k = 0; k < CNT; ++k) {
                const float xj = bcast_f(xvJ, start + k);
                Lp[k]  = flog2(fmaxf(xr1 - xj, 1.0f));
                xjd[k] = xj;
            }
        }
        lds_barrier();  // B2: expm block J published; deep/table writes done
    }
}

// Wave 0: merge + serial 64-step diagonal per phase. Per-step constants come
// from the helper-precomputed table: chain is ds_read(hoisted) -> readlane ->
// fma -> exp2 -> add. Maskless diag: lanes i <= jl have nCL=nAL=-0.0 ->
// term=1.0 exactly; readlane at step jl precedes lane jl's first
// contamination; subtract (64-lane) once at publish.
__device__ __forceinline__ void run_diag(const int lane,
                                         float (&expm_lds)[SEQ],
                                         float (&part_lds)[NH][8][64],
                                         float2 (&tbl)[2][64][64]) {
    for (int J = 0; J < 8; ++J) {
        lds_barrier();  // B1: off-diagonal partials + this block's table ready
        float acc = 0.0f;
#pragma unroll
        for (int hh = 0; hh < NH; ++hh) acc += part_lds[hh][J][lane];
#pragma unroll
        for (int jl = 0; jl < 64; ++jl) {
            const float2 nc = tbl[J & 1][jl][lane];          // off-chain (hoisted)
            const float em  = bcast_f(acc, jl);              // chain
            acc += fexp2(fmaf(nc.x, em, nc.y));              // chain
        }
        expm_lds[(J << 6) | lane] = acc - (float)(64 - lane);  // publish clean
        lds_barrier();  // B2
    }
}

__global__ void __launch_bounds__(512, 1)
act_r_kernel(const float* __restrict__ sp, const float* __restrict__ w,
             float* __restrict__ out) {
    __shared__ float  x_lds[SEQ];
    __shared__ float  expm_lds[SEQ];
    __shared__ float  part_lds[NH][8][64];   // [helper][row block][lane]
    __shared__ float2 tbl[2][64][64];        // diag (nCL,nAL), double-buffered

    const int b    = blockIdx.x;
    const int tid  = threadIdx.x;
    const int lane = tid & 63;
    // Wave id as a PROVEN-uniform SGPR value.
    const int uwid = __builtin_amdgcn_readfirstlane(tid >> 6);

    const float a   = w[0];
    const float c   = w[1];
    const float s   = w[2];
    const float tau = w[3];
    const float h   = w[4];
    const float scale = 86400.0f * h;

    for (int k = tid; k < NH * 8 * 64; k += 512) ((float*)part_lds)[k] = 0.0f;
    x_lds[tid] = sp[tid * BATCH + b] * scale;
    lds_barrier();

    // All 8 waves fill the block-0 diag table (8 cols each); consumed by
    // wave0 after phase 0's B1.
    {
        const float xr0 = x_lds[lane];     // rows == cols of block 0
        const int   s0  = uwid << 3;
#pragma unroll
        for (int k = 0; k < 8; ++k) {
            const float xj = bcast_f(xr0, s0 + k);
            const float L  = flog2(fmaxf(xr0 - xj, 1.0f));
            tbl[0][s0 + k][lane] = make_float2(-c * L, -a * L);
        }
    }

    if (uwid == 0) {
        // Serial chain is the latency-critical path: favor wave0 on SIMD0
        // issue arbitration against co-resident wave4.
        __builtin_amdgcn_s_setprio(1);
        run_diag(lane, expm_lds, part_lds, tbl);
        __builtin_amdgcn_s_setprio(0);
    } else if (uwid == 4) {
        // wave4 shares SIMD0 with wave0: smaller column share (cols 30..33).
        run_helper<4>(30, 3, lane, a, c, x_lds, expm_lds, part_lds, tbl);
    } else {
        // cols: w1:0-9 w2:10-19 w3:20-29 w5:34-43 w6:44-53 w7:54-63
        const int start = (uwid - 1) * 10 - ((uwid > 4) ? 6 : 0);
        run_helper<10>(start, uwid - 1, lane, a, c, x_lds, expm_lds, part_lds, tbl);
    }

    // ---- epilogue: all 512 threads, one output each (i = tid, skip 0)
    if (tid >= 1) {
        const float inv_ln2 = 1.4426950408889634f;
        const float q = tau / s * inv_ln2 - flog2(expm_lds[tid]) / s;
        out[(tid - 1) * BATCH + b] = 1.0f / (1.0f + fexp2(q));
    }
}

extern "C" void kernel_launch(void* const* d_in, const int* in_sizes, int n_in,
                              void* d_out, int out_size, void* d_ws, size_t ws_size,
                              hipStream_t stream) {
    const float* sp = (const float*)d_in[0];  // [512, 256, 1] f32
    const float* w  = (const float*)d_in[1];  // [5] f32
    float* out = (float*)d_out;               // [511, 256, 1] f32
    (void)in_sizes; (void)n_in; (void)out_size; (void)d_ws; (void)ws_size;

    act_r_kernel<<<dim3(BATCH), dim3(512), 0, stream>>>(sp, w, out);
}

// Round 3
// 73.924 us; speedup vs baseline: 1.0052x; 1.0052x over previous
//
#include <hip/hip_runtime.h>

#define SEQ   512
#define BATCH 256
#define NH    6   // helper partial slots (waves 1,2,3,5,6,7)

// Uniform-index lane broadcast via v_readlane (index must be SGPR/imm).
__device__ __forceinline__ float bcast_f(float v, int srcLane) {
    return __int_as_float(__builtin_amdgcn_readlane(__float_as_int(v), srcLane));
}
// gfx950: v_log_f32 is log2, v_exp_f32 is exp2.
__device__ __forceinline__ float flog2(float x) { return __builtin_amdgcn_logf(x); }
__device__ __forceinline__ float fexp2(float x) { return __builtin_amdgcn_exp2f(x); }
// Barrier draining only LDS ops (lgkmcnt); __syncthreads() would also drain vmcnt.
__device__ __forceinline__ void lds_barrier() {
    __asm__ __volatile__("s_waitcnt lgkmcnt(0)\ns_barrier" ::: "memory");
}

// Helper wave phase loop. All readlane indices are SGPR-uniform. x-only work
// (diag tables, panel L, deep xj) is computed one phase EARLY, off the
// post-publish critical path.
template <int CNT>
__device__ __forceinline__ void run_helper(const int start, const int hidx,
                                           const int lane, const float a,
                                           const float c,
                                           float (&x_lds)[SEQ],
                                           float (&expm_lds)[SEQ],
                                           float (&part_lds)[NH][8][64],
                                           float2 (&tbl)[2][64][64]) {
    float Lp[CNT];   // panel L: L(rows J, cols J-1), computed during phase J-1
    float xjd[CNT];  // deep col x values (block J-1), extracted during phase J-1
    for (int J = 0; J < 8; ++J) {
        float pj[CNT];
        if (J > 0) {
            // ---- pre-B1 critical path: only the expm-dependent part.
            const float evec = expm_lds[((J - 1) << 6) | lane];
            const float pvec = -fmaf(c, evec, a);   // p for all 64 cols, 1 op
#pragma unroll
            for (int k = 0; k < CNT; ++k) pj[k] = bcast_f(pvec, start + k);
            // panel: cols J-1 -> rows J, L precomputed last phase.
            float acc0 = 0.0f, acc1 = 0.0f;
#pragma unroll
            for (int k = 0; k < CNT; ++k) {
                const float t = fexp2(pj[k] * Lp[k]);
                if (k & 1) acc1 += t; else acc0 += t;
            }
            part_lds[hidx][J][lane] += acc0 + acc1;
        }
        lds_barrier();  // B1: panel partials for row block J ready

        if (J > 0 && J < 7) {
            // ---- deep: cols J-1 -> rows J+1..7 (overlaps wave0's diagonal).
            float xr = x_lds[((J + 1) << 6) | lane];
            for (int R = J + 1; R < 8; ++R) {
                const int Rn = (R < 7) ? R + 1 : R;              // prefetch
                const float xr_next = x_lds[(Rn << 6) | lane];
                float acc0 = 0.0f, acc1 = 0.0f;
#pragma unroll
                for (int k = 0; k < CNT; ++k) {
                    const float L = flog2(fmaxf(xr - xjd[k], 1.0f));
                    const float t = fexp2(pj[k] * L);
                    if (k & 1) acc1 += t; else acc0 += t;
                }
                part_lds[hidx][R][lane] += acc0 + acc1;
                xr = xr_next;
            }
        }
        if (J < 7) {
            // ---- x-only precompute for phase J+1 (overlaps the diagonal).
            const float xr1 = x_lds[((J + 1) << 6) | lane];  // rows/cols of block J+1
            const float xvJ = x_lds[(J << 6) | lane];        // cols of block J
#pragma unroll
            for (int k = 0; k < CNT; ++k) {
                const float xj = bcast_f(xr1, start + k);
                const float L  = flog2(fmaxf(xr1 - xj, 1.0f));
                tbl[(J + 1) & 1][start + k][lane] = make_float2(-c * L, -a * L);
            }
#pragma unroll
            for (int k = 0; k < CNT; ++k) {
                const float xj = bcast_f(xvJ, start + k);
                Lp[k]  = flog2(fmaxf(xr1 - xj, 1.0f));
                xjd[k] = xj;
            }
        }
        lds_barrier();  // B2: expm block J published; deep/table writes done
    }
}

// Wave 0: merge + serial 64-step diagonal per phase. 3-op dependent chain:
//   em[jl] = emA[jl] + t[jl-1]@jl, emA[jl] = readlane(acc_after_{jl-2}, jl)
//   z = ncx*tB + (ncx*emA + ncy)   (inner fma precomputed 2 steps early)
// Chain: readlane(t) -> fma -> exp2. acc += t has 2-step slack (off-chain).
// Maskless: junk lanes have nc=(-0,-0) -> z=-0 -> term=1.0; emA readlane at
// jl+2 reads acc_after_{jl} (lane jl+2 contaminated first at step jl+2);
// subtract (64-lane) once at publish.
__device__ __forceinline__ void run_diag(const int lane,
                                         float (&expm_lds)[SEQ],
                                         float (&part_lds)[NH][8][64],
                                         float2 (&tbl)[2][64][64]) {
    for (int J = 0; J < 8; ++J) {
        lds_barrier();  // B1: off-diagonal partials + this block's table ready
        float acc = 0.0f;
#pragma unroll
        for (int hh = 0; hh < NH; ++hh) acc += part_lds[hh][J][lane];

        // Prologue: z1 for steps 0,1 (emA = acc0 for both; t_{-1} = 0).
        float2 ncc = tbl[J & 1][0][lane];
        float2 ncn = tbl[J & 1][1][lane];
        float z1a = fmaf(ncc.x, bcast_f(acc, 0), ncc.y);
        float z1b = fmaf(ncn.x, bcast_f(acc, 1), ncn.y);
        float t = 0.0f;
#pragma unroll
        for (int jl = 0; jl < 64; ++jl) {
            const float tB = bcast_f(t, jl);        // chain: rl of t_{jl-1}
            const float z  = fmaf(ncc.x, tB, z1a);  // chain
            t = fexp2(z);                           // chain
            acc += t;                               // off-chain (2-step slack)
            z1a = z1b;
            ncc = ncn;
            if (jl + 2 < 64) {
                const float2 nc2 = tbl[J & 1][jl + 2][lane];
                const float  emA = bcast_f(acc, jl + 2);  // acc_after_{jl}, clean
                z1b = fmaf(nc2.x, emA, nc2.y);
                ncn = nc2;
            }
        }
        expm_lds[(J << 6) | lane] = acc - (float)(64 - lane);  // publish clean
        lds_barrier();  // B2
    }
}

__global__ void __launch_bounds__(512, 1)
act_r_kernel(const float* __restrict__ sp, const float* __restrict__ w,
             float* __restrict__ out) {
    __shared__ float  x_lds[SEQ];
    __shared__ float  expm_lds[SEQ];
    __shared__ float  part_lds[NH][8][64];   // [helper][row block][lane]
    __shared__ float2 tbl[2][64][64];        // diag (nCL,nAL), double-buffered

    const int b    = blockIdx.x;
    const int tid  = threadIdx.x;
    const int lane = tid & 63;
    // Wave id as a PROVEN-uniform SGPR value.
    const int uwid = __builtin_amdgcn_readfirstlane(tid >> 6);

    const float a   = w[0];
    const float c   = w[1];
    const float s   = w[2];
    const float tau = w[3];
    const float h   = w[4];
    const float scale = 86400.0f * h;

    for (int k = tid; k < NH * 8 * 64; k += 512) ((float*)part_lds)[k] = 0.0f;
    x_lds[tid] = sp[tid * BATCH + b] * scale;
    lds_barrier();

    // All 8 waves fill the block-0 diag table (8 cols each); consumed by
    // wave0 after phase 0's B1.
    {
        const float xr0 = x_lds[lane];     // rows == cols of block 0
        const int   s0  = uwid << 3;
#pragma unroll
        for (int k = 0; k < 8; ++k) {
            const float xj = bcast_f(xr0, s0 + k);
            const float L  = flog2(fmaxf(xr0 - xj, 1.0f));
            tbl[0][s0 + k][lane] = make_float2(-c * L, -a * L);
        }
    }

    if (uwid == 0) {
        // SIMD0 is wave0-exclusive (wave4 parked): no trans-pipe contention
        // against the serial chain.
        __builtin_amdgcn_s_setprio(2);
        run_diag(lane, expm_lds, part_lds, tbl);
        __builtin_amdgcn_s_setprio(0);
    } else if (uwid == 4) {
        // Parked: SIMD0 co-resident with wave0 -> do nothing but match the
        // barrier sequence (2 per phase).
        for (int J = 0; J < 8; ++J) { lds_barrier(); lds_barrier(); }
    } else {
        // 6 helpers cover 64 cols: w1:0(11) w2:11(11) w3:22(11) w5:33(11)
        //                          w6:44(10) w7:54(10)
        if (uwid < 4) {
            const int start = (uwid - 1) * 11;
            run_helper<11>(start, uwid - 1, lane, a, c, x_lds, expm_lds, part_lds, tbl);
        } else if (uwid == 5) {
            run_helper<11>(33, 3, lane, a, c, x_lds, expm_lds, part_lds, tbl);
        } else {
            const int start = 44 + (uwid - 6) * 10;
            run_helper<10>(start, uwid - 2, lane, a, c, x_lds, expm_lds, part_lds, tbl);
        }
    }

    // ---- epilogue: all 512 threads, one output each (i = tid, skip 0)
    if (tid >= 1) {
        const float inv_ln2 = 1.4426950408889634f;
        const float q = tau / s * inv_ln2 - flog2(expm_lds[tid]) / s;
        out[(tid - 1) * BATCH + b] = 1.0f / (1.0f + fexp2(q));
    }
}

extern "C" void kernel_launch(void* const* d_in, const int* in_sizes, int n_in,
                              void* d_out, int out_size, void* d_ws, size_t ws_size,
                              hipStream_t stream) {
    const float* sp = (const float*)d_in[0];  // [512, 256, 1] f32
    const float* w  = (const float*)d_in[1];  // [5] f32
    float* out = (float*)d_out;               // [511, 256, 1] f32
    (void)in_sizes; (void)n_in; (void)out_size; (void)d_ws; (void)ws_size;

    act_r_kernel<<<dim3(BATCH), dim3(512), 0, stream>>>(sp, w, out);
}